// Round 3
// baseline (206.035 us; speedup 1.0000x reference)
//
#include <hip/hip_runtime.h>

// AllInOneFlow: y = perm-scatter( scale * concat(x1, x2*exp(ls)+off) + goff ), log_jac
// MLP 32->256->256->64 (gelu,gelu,linear), B=131072. bf16-split (3-product) MFMA 16x16x32.
// This rev: 8 waves/block (64 rows), hi/lo h stored as SEPARATE bf16 LDS arrays
// (zero-unpack ds_read_b128 fragments), XOR-swizzled; coalesced-read prep.

#define NB  131072
#define DD  64
#define HH  256

typedef float f32x4 __attribute__((ext_vector_type(4)));
typedef short bf16x8 __attribute__((ext_vector_type(8)));
typedef unsigned short u16;
typedef unsigned int u32;

__device__ __align__(16) u16 g_w1h[32 * 256],  g_w1l[32 * 256];   // [n][k] n<256,k<32
__device__ __align__(16) u16 g_w2h[256 * 256], g_w2l[256 * 256];  // [n][k] 256x256
__device__ __align__(16) u16 g_w3h[64 * 256],  g_w3l[64 * 256];   // [n][k] n<64,k<256
__device__ int   g_invp[64];
__device__ float g_egls[64];
__device__ float g_sgls;

__device__ __forceinline__ u16 f2bf(float x) {
  u32 u = __float_as_uint(x);
  u32 r = u + 0x7FFFu + ((u >> 16) & 1u); // RNE
  return (u16)(r >> 16);
}
__device__ __forceinline__ float bf2f(u16 b) {
  return __uint_as_float(((u32)b) << 16);
}
__device__ __forceinline__ float fast_tanh(float z) {
  float e = __expf(2.0f * z);
  return 1.0f - 2.0f * __builtin_amdgcn_rcpf(e + 1.0f);
}
__device__ __forceinline__ float gelu_tanh(float x) {
  float u = x * x;
  float inner = x * (0.7978845608028654f + 0.03567740814183556f * u);
  return 0.5f * x * (1.0f + fast_tanh(inner));
}
__device__ __forceinline__ void split8(const float* v, bf16x8& hi, bf16x8& lo) {
#pragma unroll
  for (int j = 0; j < 8; ++j) {
    u16 h = f2bf(v[j]);
    hi[j] = (short)h;
    lo[j] = (short)f2bf(v[j] - bf2f(h));
  }
}

#define MFMA(a, b, c) __builtin_amdgcn_mfma_f32_16x16x32_bf16((a), (b), (c), 0, 0, 0)
// u16 index into h arrays: row-major [64][256] with XOR swizzle on k (bits 3-5 ^ row&7).
// Preserves 8-elem (16B) groups; makes stride-512B column reads conflict-free.
#define HIDX(row, k) (((row) << 8) + ((k) ^ (((row) & 7) << 3)))
#define LO_OFF 16384  // u16 offset of lo array (+32 KiB)

// ---------------- prep: coalesced-read transpose + bf16-split ----------------
__global__ void flow_prep(const float* __restrict__ W1, const float* __restrict__ W2,
                          const float* __restrict__ W3, const int* __restrict__ perm,
                          const float* __restrict__ gin) {
  int idx = blockIdx.x * blockDim.x + threadIdx.x;
  int stride = gridDim.x * blockDim.x;
  for (int i = idx; i < 256 * 256; i += stride) { // read W2[k][n] coalesced
    int k = i >> 8, n = i & 255;
    float v = W2[i];
    u16 h = f2bf(v);
    g_w2h[n * 256 + k] = h; g_w2l[n * 256 + k] = f2bf(v - bf2f(h));
  }
  for (int i = idx; i < 32 * 256; i += stride) { // W1[k][n]
    int k = i >> 8, n = i & 255;
    float v = W1[i];
    u16 h = f2bf(v);
    g_w1h[n * 32 + k] = h; g_w1l[n * 32 + k] = f2bf(v - bf2f(h));
  }
  for (int i = idx; i < 256 * 64; i += stride) { // W3[k][n]
    int k = i >> 6, n = i & 63;
    float v = W3[i];
    u16 h = f2bf(v);
    g_w3h[n * 256 + k] = h; g_w3l[n * 256 + k] = f2bf(v - bf2f(h));
  }
  if (blockIdx.x == 0 && threadIdx.x < 64) {
    int t = threadIdx.x;
    g_invp[perm[t]] = t;
    float gl = 4.0f * tanhf(gin[t] * 0.25f);
    g_egls[t] = expf(gl);
    float s = gl;
#pragma unroll
    for (int m = 1; m < 64; m <<= 1) s += __shfl_xor(s, m);
    if (t == 0) g_sgls = s;
  }
}

// ---------------- main: 64 rows/block, 8 waves; waves split N ----------------
// LDS 64 KiB: h_hi bf16[64][256] at 0, h_lo at +32KB. x-stage (f32, stride 68,
// 17.4KB) and params/y (f32, stride 68) overlay the same region (time-multiplexed).
__global__ __launch_bounds__(512, 4) void flow_main(
    const float* __restrict__ x, const int* __restrict__ perm,
    const float* __restrict__ b1, const float* __restrict__ b2,
    const float* __restrict__ b3, const float* __restrict__ goff,
    float* __restrict__ out) {
  __shared__ u32 lds32[16384]; // 64 KiB exactly
  u16* hb = (u16*)lds32;
  float* ldsf = (float*)lds32;
  const int tid = threadIdx.x;
  const int wave = tid >> 6, lane = tid & 63;
  const int g = lane >> 4, lm = lane & 15;
  const size_t row0 = (size_t)blockIdx.x * 64;

  // Phase A: stage x (64x64 f32), stride 68
  {
    const float4* xv = (const float4*)(x + row0 * DD);
#pragma unroll
    for (int t = 0; t < 2; ++t) {
      int i = tid + t * 512;
      int r = i >> 4, c4 = i & 15;
      float4 v = xv[i];
      *(float4*)(ldsf + r * 68 + c4 * 4) = v;
    }
  }
  __syncthreads();

  // Phase B: inverse-perm gather. A-fragments for GEMM1 (all 4 row-tiles) +
  // x1/x2 for this wave's 8 epilogue rows (row = wave*8 + g*2 + rr, col = ct*16+lm).
  int ic[8];
#pragma unroll
  for (int j = 0; j < 8; ++j) ic[j] = g_invp[g * 8 + j];
  bf16x8 a1h[4], a1l[4];
#pragma unroll
  for (int rt = 0; rt < 4; ++rt) {
    float v[8];
#pragma unroll
    for (int j = 0; j < 8; ++j) v[j] = ldsf[(rt * 16 + lm) * 68 + ic[j]];
    split8(v, a1h[rt], a1l[rt]);
  }
  float x1cd[4], x2cd[4];
#pragma unroll
  for (int ct = 0; ct < 2; ++ct) {
    int c1 = g_invp[ct * 16 + lm];
    int c2 = g_invp[32 + ct * 16 + lm];
#pragma unroll
    for (int rr = 0; rr < 2; ++rr) {
      int row = wave * 8 + g * 2 + rr;
      x1cd[ct * 2 + rr] = ldsf[row * 68 + c1];
      x2cd[ct * 2 + rr] = ldsf[row * 68 + c2];
    }
  }
  __syncthreads(); // x-stage dead; region becomes h_hi/h_lo

  // Phase C: GEMM1 (K=32). Wave owns col-tiles {wave*2, wave*2+1}.
#pragma unroll
  for (int c = 0; c < 2; ++c) {
    int col = (wave * 2 + c) * 16 + lm;
    float bb = b1[col];
    f32x4 acc[4];
#pragma unroll
    for (int rt = 0; rt < 4; ++rt) acc[rt] = f32x4{bb, bb, bb, bb};
    bf16x8 bh = *(const bf16x8*)(g_w1h + col * 32 + g * 8);
    bf16x8 bl = *(const bf16x8*)(g_w1l + col * 32 + g * 8);
#pragma unroll
    for (int rt = 0; rt < 4; ++rt) {
      acc[rt] = MFMA(a1h[rt], bh, acc[rt]);
      acc[rt] = MFMA(a1h[rt], bl, acc[rt]);
      acc[rt] = MFMA(a1l[rt], bh, acc[rt]);
    }
#pragma unroll
    for (int rt = 0; rt < 4; ++rt)
#pragma unroll
      for (int r = 0; r < 4; ++r) {
        int row = rt * 16 + g * 4 + r;
        float hv = gelu_tanh(acc[rt][r]);
        u16 hbits = f2bf(hv);
        int hidx = HIDX(row, col);
        hb[hidx] = hbits;
        hb[hidx + LO_OFF] = f2bf(hv - bf2f(hbits));
      }
  }
  __syncthreads();

  // Phase D: GEMM2 (K=256). A-frags: raw ds_read_b128, no unpack.
  f32x4 acc2[2][4];
#pragma unroll
  for (int c = 0; c < 2; ++c) {
    float bb = b2[(wave * 2 + c) * 16 + lm];
#pragma unroll
    for (int rt = 0; rt < 4; ++rt) acc2[c][rt] = f32x4{bb, bb, bb, bb};
  }
  const int swz = (lm & 7) << 3;
#pragma unroll 2
  for (int kk = 0; kk < 8; ++kk) {
    int koff = (kk * 32 + g * 8) ^ swz; // lane-constant XOR, 8-aligned
    bf16x8 ah[4], al[4];
#pragma unroll
    for (int rt = 0; rt < 4; ++rt) {
      const u16* p = hb + ((rt * 16 + lm) << 8) + koff;
      ah[rt] = *(const bf16x8*)(p);
      al[rt] = *(const bf16x8*)(p + LO_OFF);
    }
#pragma unroll
    for (int c = 0; c < 2; ++c) {
      int off = ((wave * 2 + c) * 16 + lm) * 256 + kk * 32 + g * 8;
      bf16x8 bh = *(const bf16x8*)(g_w2h + off);
      bf16x8 bl = *(const bf16x8*)(g_w2l + off);
#pragma unroll
      for (int rt = 0; rt < 4; ++rt) {
        acc2[c][rt] = MFMA(ah[rt], bh, acc2[c][rt]);
        acc2[c][rt] = MFMA(ah[rt], bl, acc2[c][rt]);
        acc2[c][rt] = MFMA(al[rt], bh, acc2[c][rt]);
      }
    }
  }
  __syncthreads(); // all h1 reads done before overwrite
#pragma unroll
  for (int c = 0; c < 2; ++c) {
    int col = (wave * 2 + c) * 16 + lm;
#pragma unroll
    for (int rt = 0; rt < 4; ++rt)
#pragma unroll
      for (int r = 0; r < 4; ++r) {
        int row = rt * 16 + g * 4 + r;
        float hv = gelu_tanh(acc2[c][rt][r]);
        u16 hbits = f2bf(hv);
        int hidx = HIDX(row, col);
        hb[hidx] = hbits;
        hb[hidx + LO_OFF] = f2bf(hv - bf2f(hbits));
      }
  }
  __syncthreads();

  // Phase F: GEMM3 (K=256, N=64). Wave owns col-tile (wave&3), row-tiles
  // {2*(wave>>2), 2*(wave>>2)+1}. Full K per wave; no partial sums.
  const int ct3 = wave & 3, rtb = (wave >> 2) * 2;
  f32x4 acc3[2];
  {
    float bb = b3[ct3 * 16 + lm];
    acc3[0] = f32x4{bb, bb, bb, bb};
    acc3[1] = f32x4{bb, bb, bb, bb};
  }
#pragma unroll 2
  for (int kk = 0; kk < 8; ++kk) {
    int koff = (kk * 32 + g * 8) ^ swz;
    bf16x8 ah[2], al[2];
#pragma unroll
    for (int q = 0; q < 2; ++q) {
      const u16* p = hb + (((rtb + q) * 16 + lm) << 8) + koff;
      ah[q] = *(const bf16x8*)(p);
      al[q] = *(const bf16x8*)(p + LO_OFF);
    }
    int off = (ct3 * 16 + lm) * 256 + kk * 32 + g * 8;
    bf16x8 bh = *(const bf16x8*)(g_w3h + off);
    bf16x8 bl = *(const bf16x8*)(g_w3l + off);
#pragma unroll
    for (int q = 0; q < 2; ++q) {
      acc3[q] = MFMA(ah[q], bh, acc3[q]);
      acc3[q] = MFMA(ah[q], bl, acc3[q]);
      acc3[q] = MFMA(al[q], bh, acc3[q]);
    }
  }
  __syncthreads(); // all h2 reads done; region becomes params (f32, stride 68)
#pragma unroll
  for (int q = 0; q < 2; ++q)
#pragma unroll
    for (int r = 0; r < 4; ++r)
      ldsf[((rtb + q) * 16 + g * 4 + r) * 68 + ct3 * 16 + lm] = acc3[q][r];
  __syncthreads();

  // Phase G: epilogue, 8 rows/wave (row = wave*8 + g*2 + rr). Read all params
  // into regs first, then overwrite region with final y, reduce log_jac, store.
  float pls[4], pof[4];
#pragma unroll
  for (int ct = 0; ct < 2; ++ct)
#pragma unroll
    for (int rr = 0; rr < 2; ++rr) {
      int row = wave * 8 + g * 2 + rr;
      pls[ct * 2 + rr] = ldsf[row * 68 + ct * 16 + lm];
      pof[ct * 2 + rr] = ldsf[row * 68 + 32 + ct * 16 + lm];
    }
  float sg = g_sgls;
  float lj[2] = {0.f, 0.f};
#pragma unroll
  for (int ct = 0; ct < 2; ++ct) {
    int c1 = ct * 16 + lm, c2v = 32 + ct * 16 + lm;
    float e1 = g_egls[c1], o1 = goff[c1];
    float e2 = g_egls[c2v], o2 = goff[c2v];
#pragma unroll
    for (int rr = 0; rr < 2; ++rr) {
      int row = wave * 8 + g * 2 + rr;
      float ls = 2.0f * fast_tanh(0.1f * pls[ct * 2 + rr]);
      lj[rr] += ls;
      float y2 = x2cd[ct * 2 + rr] * __expf(ls) + pof[ct * 2 + rr];
      ldsf[row * 68 + c1]  = x1cd[ct * 2 + rr] * e1 + o1;
      ldsf[row * 68 + c2v] = y2 * e2 + o2;
    }
  }
#pragma unroll
  for (int rr = 0; rr < 2; ++rr) {
    float v = lj[rr];
    v += __shfl_xor(v, 1); v += __shfl_xor(v, 2);
    v += __shfl_xor(v, 4); v += __shfl_xor(v, 8);
    if (lm == 0) {
      size_t row = row0 + wave * 8 + g * 2 + rr;
      out[(size_t)NB * DD + row] = v + sg;
    }
  }
  int pj = perm[lane];
#pragma unroll
  for (int rl = 0; rl < 8; ++rl) {
    size_t row = row0 + wave * 8 + rl;
    out[row * DD + lane] = ldsf[(wave * 8 + rl) * 68 + pj];
  }
}

extern "C" void kernel_launch(void* const* d_in, const int* in_sizes, int n_in,
                              void* d_out, int out_size, void* d_ws, size_t ws_size,
                              hipStream_t stream) {
  const float* x    = (const float*)d_in[0];
  const int*   perm = (const int*)d_in[1];
  const float* W1   = (const float*)d_in[2];
  const float* b1   = (const float*)d_in[3];
  const float* W2   = (const float*)d_in[4];
  const float* b2   = (const float*)d_in[5];
  const float* W3   = (const float*)d_in[6];
  const float* b3   = (const float*)d_in[7];
  const float* gls  = (const float*)d_in[8];
  const float* goff = (const float*)d_in[9];
  (void)in_sizes; (void)n_in; (void)d_ws; (void)ws_size; (void)out_size;

  flow_prep<<<256, 256, 0, stream>>>(W1, W2, W3, perm, gls);
  flow_main<<<NB / 64, 512, 0, stream>>>(x, perm, b1, b2, b3, goff, (float*)d_out);
}

// Round 4
// 199.697 us; speedup vs baseline: 1.0317x; 1.0317x over previous
//
#include <hip/hip_runtime.h>

// AllInOneFlow: y = perm-scatter( scale * concat(x1, x2*exp(ls)+off) + goff ), log_jac
// MLP 32->256->256->64 (gelu,gelu,linear), B=131072. bf16-split (3-product) MFMA 16x16x32.
// This rev: OPERAND-SWAPPED MFMA (A=weights, B=activations) so epilogue writes are
// b64/b128 not scalar b16; v_cvt_pk_bf16_f32 packing; full-unroll K loops; tiled prep.

#define NB  131072
#define DD  64
#define HH  256

typedef float f32x4 __attribute__((ext_vector_type(4)));
typedef short bf16x8 __attribute__((ext_vector_type(8)));
typedef unsigned short u16;
typedef unsigned int u32;
typedef u32 u32x2 __attribute__((ext_vector_type(2)));

__device__ __align__(16) u16 g_w1h[32 * 256],  g_w1l[32 * 256];   // [n][k] n<256,k<32
__device__ __align__(16) u16 g_w2h[256 * 256], g_w2l[256 * 256];  // [n][k] 256x256
__device__ __align__(16) u16 g_w3h[64 * 256],  g_w3l[64 * 256];   // [n][k] n<64,k<256
__device__ int   g_invp[64];
__device__ float g_egls[64];
__device__ float g_sgls;

__device__ __forceinline__ u16 f2bf(float x) {
  u32 u = __float_as_uint(x);
  u32 r = u + 0x7FFFu + ((u >> 16) & 1u); // RNE
  return (u16)(r >> 16);
}
__device__ __forceinline__ float bf2f(u16 b) {
  return __uint_as_float(((u32)b) << 16);
}
// packed 2x f32->bf16 RNE: low16 = cvt(a), high16 = cvt(b)
__device__ __forceinline__ u32 pk2(float a, float b) {
  u32 r;
  asm("v_cvt_pk_bf16_f32 %0, %1, %2" : "=v"(r) : "v"(a), "v"(b));
  return r;
}
__device__ __forceinline__ float fast_tanh(float z) {
  float e = __expf(2.0f * z);
  return 1.0f - 2.0f * __builtin_amdgcn_rcpf(e + 1.0f);
}
__device__ __forceinline__ float gelu_tanh(float x) {
  float u = x * x;
  float inner = x * (0.7978845608028654f + 0.03567740814183556f * u);
  return 0.5f * x * (1.0f + fast_tanh(inner));
}
// f32[8] -> bf16 hi/lo fragments via cvt_pk (pair order matches u32 lanes of bf16x8)
__device__ __forceinline__ void split8(const float* v, bf16x8& hi, bf16x8& lo) {
  u32* hw = (u32*)&hi; u32* lw = (u32*)&lo;
#pragma unroll
  for (int j = 0; j < 4; ++j) {
    float a = v[2 * j], b = v[2 * j + 1];
    u32 p = pk2(a, b);
    float la = a - __uint_as_float(p << 16);
    float lb = b - __uint_as_float(p & 0xffff0000u);
    hw[j] = p; lw[j] = pk2(la, lb);
  }
}

#define MFMA(a, b, c) __builtin_amdgcn_mfma_f32_16x16x32_bf16((a), (b), (c), 0, 0, 0)
// u16 word index into h arrays [64 rows m][256 cols n], XOR swizzle on low coord
// (bits 3-5 ^ m&7). Same involution on write (n) and read (k); preserves 8-elem chunks.
#define LO_OFF 16384  // u16 offset of lo array (+32 KiB)

// gelu + split-once + b64 stores of 4 consecutive n at row m (hi and lo arrays)
__device__ __forceinline__ void store_h4(u16* hb, int m, int n0, f32x4 accv) {
  float g0 = gelu_tanh(accv[0]), g1 = gelu_tanh(accv[1]);
  float g2 = gelu_tanh(accv[2]), g3 = gelu_tanh(accv[3]);
  u32 h01 = pk2(g0, g1), h23 = pk2(g2, g3);
  float l0 = g0 - __uint_as_float(h01 << 16);
  float l1 = g1 - __uint_as_float(h01 & 0xffff0000u);
  float l2 = g2 - __uint_as_float(h23 << 16);
  float l3 = g3 - __uint_as_float(h23 & 0xffff0000u);
  u32 l01 = pk2(l0, l1), l23 = pk2(l2, l3);
  int idx = (m << 8) + (n0 ^ ((m & 7) << 3));
  *(u32x2*)(hb + idx) = u32x2{h01, h23};
  *(u32x2*)(hb + idx + LO_OFF) = u32x2{l01, l23};
}

// ---------------- prep: LDS-tiled transpose, coalesced both sides ----------------
__global__ void flow_prep(const float* __restrict__ W1, const float* __restrict__ W2,
                          const float* __restrict__ W3, const int* __restrict__ perm,
                          const float* __restrict__ gin) {
  __shared__ float t[64][65];
  const int b = blockIdx.x, tid = threadIdx.x;
  if (b < 16) { // W2 [256k][256n]: tile kt,nt of 64x64
    int kt = (b & 3) * 64, nt = (b >> 2) * 64;
#pragma unroll
    for (int it = 0; it < 16; ++it) {
      int idx = it * 256 + tid, r = idx >> 6, c = idx & 63;
      t[r][c] = W2[(kt + r) * 256 + nt + c];
    }
    __syncthreads();
#pragma unroll
    for (int it = 0; it < 16; ++it) {
      int idx = it * 256 + tid, cc = idx >> 6, rr = idx & 63;
      float v = t[rr][cc];
      u16 h = f2bf(v);
      g_w2h[(nt + cc) * 256 + kt + rr] = h;
      g_w2l[(nt + cc) * 256 + kt + rr] = f2bf(v - bf2f(h));
    }
  } else if (b < 20) { // W1 [32k][256n]: n-tile of 64
    int nt = (b - 16) * 64;
#pragma unroll
    for (int it = 0; it < 8; ++it) {
      int idx = it * 256 + tid, r = idx >> 6, c = idx & 63;
      t[r][c] = W1[r * 256 + nt + c];
    }
    __syncthreads();
#pragma unroll
    for (int it = 0; it < 8; ++it) {
      int idx = it * 256 + tid, cc = idx >> 5, rr = idx & 31;
      float v = t[rr][cc];
      u16 h = f2bf(v);
      g_w1h[(nt + cc) * 32 + rr] = h;
      g_w1l[(nt + cc) * 32 + rr] = f2bf(v - bf2f(h));
    }
  } else if (b < 24) { // W3 [256k][64n]: k-tile of 64
    int kt = (b - 20) * 64;
#pragma unroll
    for (int it = 0; it < 16; ++it) {
      int idx = it * 256 + tid, r = idx >> 6, c = idx & 63;
      t[r][c] = W3[(kt + r) * 64 + c];
    }
    __syncthreads();
#pragma unroll
    for (int it = 0; it < 16; ++it) {
      int idx = it * 256 + tid, cc = idx >> 6, rr = idx & 63;
      float v = t[rr][cc];
      u16 h = f2bf(v);
      g_w3h[cc * 256 + kt + rr] = h;
      g_w3l[cc * 256 + kt + rr] = f2bf(v - bf2f(h));
    }
  } else { // perm, inv perm, global scale
    if (tid < 64) {
      int tt = tid;
      g_invp[perm[tt]] = tt;
      float gl = 4.0f * tanhf(gin[tt] * 0.25f);
      g_egls[tt] = expf(gl);
      float s = gl;
#pragma unroll
      for (int m = 1; m < 64; m <<= 1) s += __shfl_xor(s, m);
      if (tt == 0) g_sgls = s;
    }
  }
}

// ---------------- main: 64 rows/block, 8 waves; waves split N ----------------
// LDS 64 KiB: h_hi bf16[64][256] at 0, h_lo at +32KB; x-stage / params overlay (f32,
// stride 68). MFMA operand order: A = weight [n][k], B = activation [k][m] ->
// D[n][m]: thread (g,lm) holds rows n = g*4+{0..3}, col m = lm (per m89 C/D map).
__global__ __launch_bounds__(512, 4) void flow_main(
    const float* __restrict__ x, const int* __restrict__ perm,
    const float* __restrict__ b1, const float* __restrict__ b2,
    const float* __restrict__ b3, const float* __restrict__ goff,
    float* __restrict__ out) {
  __shared__ u32 lds32[16384]; // 64 KiB exactly
  u16* hb = (u16*)lds32;
  float* ldsf = (float*)lds32;
  const int tid = threadIdx.x;
  const int wave = tid >> 6, lane = tid & 63;
  const int g = lane >> 4, lm = lane & 15;
  const size_t row0 = (size_t)blockIdx.x * 64;

  // Phase A: stage x (64x64 f32), stride 68
  {
    const float4* xv = (const float4*)(x + row0 * DD);
#pragma unroll
    for (int t = 0; t < 2; ++t) {
      int i = tid + t * 512;
      int r = i >> 4, c4 = i & 15;
      float4 v = xv[i];
      *(float4*)(ldsf + r * 68 + c4 * 4) = v;
    }
  }
  __syncthreads();

  // Phase B: inverse-perm gather -> GEMM1 B-fragments (activations), plus x1/x2
  // for this wave's 8 epilogue rows (row = wave*8 + g*2 + rr, col = ct*16+lm).
  int ic[8];
#pragma unroll
  for (int j = 0; j < 8; ++j) ic[j] = g_invp[g * 8 + j];
  bf16x8 bxh[4], bxl[4]; // B-frag: [k = g*8+j][m = mt*16+lm]
#pragma unroll
  for (int mt = 0; mt < 4; ++mt) {
    float v[8];
#pragma unroll
    for (int j = 0; j < 8; ++j) v[j] = ldsf[(mt * 16 + lm) * 68 + ic[j]];
    split8(v, bxh[mt], bxl[mt]);
  }
  float x1cd[4], x2cd[4];
#pragma unroll
  for (int ct = 0; ct < 2; ++ct) {
    int c1 = g_invp[ct * 16 + lm];
    int c2 = g_invp[32 + ct * 16 + lm];
#pragma unroll
    for (int rr = 0; rr < 2; ++rr) {
      int row = wave * 8 + g * 2 + rr;
      x1cd[ct * 2 + rr] = ldsf[row * 68 + c1];
      x2cd[ct * 2 + rr] = ldsf[row * 68 + c2];
    }
  }
  __syncthreads(); // x-stage dead; region becomes h_hi/h_lo

  // Phase C: GEMM1 (K=32, one MFMA-chain per tile). Wave owns n-tiles {2w, 2w+1}.
#pragma unroll
  for (int c = 0; c < 2; ++c) {
    int nt = wave * 2 + c;
    bf16x8 wh = *(const bf16x8*)(g_w1h + (nt * 16 + lm) * 32 + g * 8);
    bf16x8 wl = *(const bf16x8*)(g_w1l + (nt * 16 + lm) * 32 + g * 8);
    f32x4 bi = *(const f32x4*)(b1 + nt * 16 + g * 4);
#pragma unroll
    for (int mt = 0; mt < 4; ++mt) {
      f32x4 acc = bi;
      acc = MFMA(wh, bxh[mt], acc);
      acc = MFMA(wh, bxl[mt], acc);
      acc = MFMA(wl, bxh[mt], acc);
      store_h4(hb, mt * 16 + lm, nt * 16 + g * 4, acc);
    }
  }
  __syncthreads();

  // Phase D: GEMM2 (K=256). A = W2 frags (global/L2), B = h1 frags (LDS b128).
  f32x4 acc2[2][4];
#pragma unroll
  for (int c = 0; c < 2; ++c) {
    f32x4 bi = *(const f32x4*)(b2 + (wave * 2 + c) * 16 + g * 4);
#pragma unroll
    for (int mt = 0; mt < 4; ++mt) acc2[c][mt] = bi;
  }
  const int swz = (lm & 7) << 3;
#pragma unroll
  for (int kk = 0; kk < 8; ++kk) {
    int koff = (kk * 32 + g * 8) ^ swz;
    bf16x8 bh[4], bl[4];
#pragma unroll
    for (int mt = 0; mt < 4; ++mt) {
      const u16* p = hb + ((mt * 16 + lm) << 8) + koff;
      bh[mt] = *(const bf16x8*)p;
      bl[mt] = *(const bf16x8*)(p + LO_OFF);
    }
#pragma unroll
    for (int c = 0; c < 2; ++c) {
      int off = ((wave * 2 + c) * 16 + lm) * 256 + kk * 32 + g * 8;
      bf16x8 wh = *(const bf16x8*)(g_w2h + off);
      bf16x8 wl = *(const bf16x8*)(g_w2l + off);
#pragma unroll
      for (int mt = 0; mt < 4; ++mt) {
        acc2[c][mt] = MFMA(wh, bh[mt], acc2[c][mt]);
        acc2[c][mt] = MFMA(wh, bl[mt], acc2[c][mt]);
        acc2[c][mt] = MFMA(wl, bh[mt], acc2[c][mt]);
      }
    }
  }
  // issue GEMM3 kk=0 weight loads now (no LDS dependency; in flight over barrier)
  const int ct3 = wave & 3, rtb = (wave >> 2) * 2;
  bf16x8 w3h0 = *(const bf16x8*)(g_w3h + (ct3 * 16 + lm) * 256 + g * 8);
  bf16x8 w3l0 = *(const bf16x8*)(g_w3l + (ct3 * 16 + lm) * 256 + g * 8);
  __syncthreads(); // all h1 reads done before overwrite
#pragma unroll
  for (int c = 0; c < 2; ++c)
#pragma unroll
    for (int mt = 0; mt < 4; ++mt)
      store_h4(hb, mt * 16 + lm, (wave * 2 + c) * 16 + g * 4, acc2[c][mt]);
  __syncthreads();

  // Phase F: GEMM3 (K=256, N=64). Wave: n-tile ct3, m-tiles {rtb, rtb+1}.
  f32x4 acc3[2];
  {
    f32x4 bi = *(const f32x4*)(b3 + ct3 * 16 + g * 4);
    acc3[0] = bi; acc3[1] = bi;
  }
#pragma unroll
  for (int kk = 0; kk < 8; ++kk) {
    int koff = (kk * 32 + g * 8) ^ swz;
    bf16x8 bh[2], bl[2];
#pragma unroll
    for (int q = 0; q < 2; ++q) {
      const u16* p = hb + (((rtb + q) * 16 + lm) << 8) + koff;
      bh[q] = *(const bf16x8*)p;
      bl[q] = *(const bf16x8*)(p + LO_OFF);
    }
    bf16x8 wh, wl;
    if (kk == 0) { wh = w3h0; wl = w3l0; }
    else {
      int off = (ct3 * 16 + lm) * 256 + kk * 32 + g * 8;
      wh = *(const bf16x8*)(g_w3h + off);
      wl = *(const bf16x8*)(g_w3l + off);
    }
#pragma unroll
    for (int q = 0; q < 2; ++q) {
      acc3[q] = MFMA(wh, bh[q], acc3[q]);
      acc3[q] = MFMA(wh, bl[q], acc3[q]);
      acc3[q] = MFMA(wl, bh[q], acc3[q]);
    }
  }
  __syncthreads(); // all h2 reads done; region becomes params (f32, stride 68)
#pragma unroll
  for (int q = 0; q < 2; ++q)
    *(f32x4*)(ldsf + ((rtb + q) * 16 + lm) * 68 + ct3 * 16 + g * 4) = acc3[q];
  __syncthreads();

  // Phase G: epilogue, 8 rows/wave (row = wave*8 + g*2 + rr).
  float pls[4], pof[4];
#pragma unroll
  for (int ct = 0; ct < 2; ++ct)
#pragma unroll
    for (int rr = 0; rr < 2; ++rr) {
      int row = wave * 8 + g * 2 + rr;
      pls[ct * 2 + rr] = ldsf[row * 68 + ct * 16 + lm];
      pof[ct * 2 + rr] = ldsf[row * 68 + 32 + ct * 16 + lm];
    }
  float sg = g_sgls;
  float lj[2] = {0.f, 0.f};
#pragma unroll
  for (int ct = 0; ct < 2; ++ct) {
    int c1 = ct * 16 + lm, c2v = 32 + ct * 16 + lm;
    float e1 = g_egls[c1], o1 = goff[c1];
    float e2 = g_egls[c2v], o2 = goff[c2v];
#pragma unroll
    for (int rr = 0; rr < 2; ++rr) {
      int row = wave * 8 + g * 2 + rr;
      float ls = 2.0f * fast_tanh(0.1f * pls[ct * 2 + rr]);
      lj[rr] += ls;
      float y2 = x2cd[ct * 2 + rr] * __expf(ls) + pof[ct * 2 + rr];
      ldsf[row * 68 + c1]  = x1cd[ct * 2 + rr] * e1 + o1;
      ldsf[row * 68 + c2v] = y2 * e2 + o2;
    }
  }
#pragma unroll
  for (int rr = 0; rr < 2; ++rr) {
    float v = lj[rr];
    v += __shfl_xor(v, 1); v += __shfl_xor(v, 2);
    v += __shfl_xor(v, 4); v += __shfl_xor(v, 8);
    if (lm == 0) {
      size_t row = row0 + wave * 8 + g * 2 + rr;
      out[(size_t)NB * DD + row] = v + sg;
    }
  }
  int pj = perm[lane];
#pragma unroll
  for (int rl = 0; rl < 8; ++rl) {
    size_t row = row0 + wave * 8 + rl;
    out[row * DD + lane] = ldsf[(wave * 8 + rl) * 68 + pj];
  }
}

extern "C" void kernel_launch(void* const* d_in, const int* in_sizes, int n_in,
                              void* d_out, int out_size, void* d_ws, size_t ws_size,
                              hipStream_t stream) {
  const float* x    = (const float*)d_in[0];
  const int*   perm = (const int*)d_in[1];
  const float* W1   = (const float*)d_in[2];
  const float* b1   = (const float*)d_in[3];
  const float* W2   = (const float*)d_in[4];
  const float* b2   = (const float*)d_in[5];
  const float* W3   = (const float*)d_in[6];
  const float* b3   = (const float*)d_in[7];
  const float* gls  = (const float*)d_in[8];
  const float* goff = (const float*)d_in[9];
  (void)in_sizes; (void)n_in; (void)d_ws; (void)ws_size; (void)out_size;

  flow_prep<<<25, 256, 0, stream>>>(W1, W2, W3, perm, gls);
  flow_main<<<NB / 64, 512, 0, stream>>>(x, perm, b1, b2, b3, goff, (float*)d_out);
}